// Round 10
// baseline (535.828 us; speedup 1.0000x reference)
//
#include <hip/hip_runtime.h>
#include <math.h>

constexpr int Bc = 2;
constexpr int Nc = 50000;
constexpr int Ec = 250000;
constexpr int Dc = 64;
constexpr int TOT = Bc * Ec;            // 500000
constexpr int NT_TILES = 7816;          // ceil(TOT/64)
constexpr int TOT_PAD = NT_TILES * 64;  // 500224
constexpr int SCAN_NBLK = (Nc + 255) / 256;   // 196

typedef __attribute__((ext_vector_type(8))) short short8;
typedef __attribute__((ext_vector_type(8))) unsigned short ushort8;
typedef __attribute__((ext_vector_type(4))) float f32x4;

__device__ inline unsigned short f2bf(float f) {
    unsigned int u = __builtin_bit_cast(unsigned int, f);
    unsigned int r = (u + 0x7fffu + ((u >> 16) & 1u)) >> 16;
    return (unsigned short)r;
}
__device__ inline float bf2f(unsigned short s) {
    unsigned int u = ((unsigned int)s) << 16;
    return __builtin_bit_cast(float, u);
}

// ---------------- CSR build (by dst) ----------------
__global__ __launch_bounds__(256) void csr_zero(int* __restrict__ counts)
{
    int i = blockIdx.x * 256 + threadIdx.x;
    if (i < Nc) counts[i] = 0;
}

__global__ __launch_bounds__(256) void csr_count(const int* __restrict__ dst,
                                                 int* __restrict__ counts)
{
    int e = blockIdx.x * 256 + threadIdx.x;
    if (e < Ec) atomicAdd(&counts[dst[e]], 1);
}

// hierarchical scan, level 1: block-local inclusive scan, emit block sums
__global__ __launch_bounds__(256) void scan_partial(const int* __restrict__ counts,
                                                    int* __restrict__ bsum)
{
    __shared__ int sm[256];
    int tid = threadIdx.x;
    int i = blockIdx.x * 256 + tid;
    int c = (i < Nc) ? counts[i] : 0;
    sm[tid] = c;
    __syncthreads();
    #pragma unroll
    for (int off = 1; off < 256; off <<= 1) {
        int v = (tid >= off) ? sm[tid - off] : 0;
        __syncthreads();
        sm[tid] += v;
        __syncthreads();
    }
    if (tid == 255) bsum[blockIdx.x] = sm[255];
}

// level 2: exclusive scan of block sums (1 block)
__global__ __launch_bounds__(256) void scan_bsum(int* __restrict__ bsum)
{
    __shared__ int sm[256];
    int tid = threadIdx.x;
    int v = (tid < SCAN_NBLK) ? bsum[tid] : 0;
    sm[tid] = v;
    __syncthreads();
    #pragma unroll
    for (int off = 1; off < 256; off <<= 1) {
        int u = (tid >= off) ? sm[tid - off] : 0;
        __syncthreads();
        sm[tid] += u;
        __syncthreads();
    }
    if (tid < SCAN_NBLK) bsum[tid] = sm[tid] - v;   // exclusive
}

// level 3: offsets/cursor = bbase + local exclusive scan
__global__ __launch_bounds__(256) void scan_final(const int* __restrict__ counts,
                                                  const int* __restrict__ bsum,
                                                  int* __restrict__ offsets,
                                                  int* __restrict__ cursor)
{
    __shared__ int sm[256];
    int tid = threadIdx.x;
    int i = blockIdx.x * 256 + tid;
    int c = (i < Nc) ? counts[i] : 0;
    sm[tid] = c;
    __syncthreads();
    #pragma unroll
    for (int off = 1; off < 256; off <<= 1) {
        int v = (tid >= off) ? sm[tid - off] : 0;
        __syncthreads();
        sm[tid] += v;
        __syncthreads();
    }
    if (i < Nc) {
        int o = bsum[blockIdx.x] + sm[tid] - c;
        offsets[i] = o;
        cursor[i] = o;
    }
    if (i == 0) offsets[Nc] = Ec;
}

// records elist (slot -> edge) and src_perm (slot -> src node)
__global__ __launch_bounds__(256) void csr_fill(const int* __restrict__ dst,
                                                const int* __restrict__ src,
                                                int* __restrict__ cursor,
                                                int* __restrict__ elist,
                                                int* __restrict__ src_perm)
{
    int e = blockIdx.x * 256 + threadIdx.x;
    if (e < Ec) {
        int p = atomicAdd(&cursor[dst[e]], 1);
        elist[p] = e;
        src_perm[p] = src[e];
    }
}

// ---------------- weight pre-swizzle: fe_W -> bf16 MFMA B-fragment table ----
// Layout per layer: 16 frags (kc*4+n) x 64 lanes x 8 bf16 = 16KB.
// B frag: col = lane&15, k = 32*kc + (lane>>4)*8 + j.
__global__ __launch_bounds__(256) void prep_W(const float* __restrict__ fe_W,
                                              unsigned short* __restrict__ Wf)
{
    int t = blockIdx.x * 256 + threadIdx.x;     // 3*1024 slots
    if (t >= 3 * 1024) return;
    int l  = t >> 10;
    int s  = t & 1023;
    int frag = s >> 6;
    int sl   = s & 63;
    int kc = frag >> 2;
    int n  = frag & 3;
    int kbase = 32 * kc + (sl >> 4) * 8;
    int col   = 16 * n + (sl & 15);
    const float* W = fe_W + (size_t)l * 2 * Dc * Dc;
    ushort8 v;
    #pragma unroll
    for (int j = 0; j < 8; ++j) v[j] = f2bf(W[(size_t)(kbase + j) * Dc + col]);
    *(ushort8*)&Wf[(size_t)t * 8] = v;
}

// ---------------- init ----------------
__global__ __launch_bounds__(256) void init_h_kernel(
    const float* __restrict__ x, const float* __restrict__ pv_W,
    const float* __restrict__ pv_b, unsigned short* __restrict__ h)
{
    int idx = blockIdx.x * blockDim.x + threadIdx.x;
    if (idx >= Bc * Nc * Dc) return;
    int bn = idx >> 6;
    int d  = idx & 63;
    float x0 = x[bn * 3 + 0];
    float x1 = x[bn * 3 + 1];
    int s = (x0 > 0.5f) ? 0 : ((x1 > 0.5f) ? 1 : 2);
    float v = pv_W[s * Dc + d] + pv_b[d];
    h[idx] = f2bf(fmaxf(v, 0.0f));
}

// g0 computed in SLOT order: gather ea[elist[p]] (random 64B reads, L2-cached),
// write g rows sequentially (fully coalesced) for both batches.
__global__ __launch_bounds__(256) void init_g_kernel(
    const float* __restrict__ ea, const float* __restrict__ pe_W,
    const float* __restrict__ pe_b, const int* __restrict__ elist,
    unsigned short* __restrict__ g)
{
    int gt = blockIdx.x * blockDim.x + threadIdx.x;
    int p  = gt >> 6;
    int d  = threadIdx.x & 63;
    if (p >= Ec) return;
    int e = elist[p];
    const float* row = ea + (size_t)e * 16;
    float acc = pe_b[d];
    #pragma unroll
    for (int t = 0; t < 16; ++t) acc = fmaf(row[t], pe_W[t * Dc + d], acc);
    unsigned short v = f2bf(fmaxf(acc, 0.0f));
    g[(size_t)p * Dc + d] = v;
    g[((size_t)Ec + p) * Dc + d] = v;
}

// ---------------- edge MLP via MFMA ----------------
// 4 waves/block; each wave owns 64 consecutive permuted edge-rows.
// A = [g_row ; h_src_row] (bf16), B = Wf (pre-swizzled bf16 frags),
// D = relu(A@B + bias) written back to g in place (own rows only).
// Fragment layouts (gfx950 16x16x32 bf16, HW-verified round 5 self-check):
//   A: row = lane&15, k = (lane>>4)*8 + j
//   B: col = lane&15, k = (lane>>4)*8 + j
//   D: col = lane&15, row = (lane>>4)*4 + reg
// Transpose per-m 16-row chunk through a small slab (LDS 16KB+9KB ->
// occupancy no longer LDS-capped). Intra-wave DS ordering makes the
// write->read->overwrite sequence safe without barriers.
__global__ __launch_bounds__(256) void edge_kernel(
    unsigned short* __restrict__ g, const unsigned short* __restrict__ h,
    const int* __restrict__ src_perm,
    const unsigned short* __restrict__ Wf /* [16][64][8] bf16 */,
    const float* __restrict__ bias)
{
    __shared__ unsigned short ldsB[16 * 64 * 8];   // 16KB
    __shared__ unsigned short slab[4][16 * 72];    // 9KB: per-wave 16-row chunk

    int tid = threadIdx.x;
    int wid = tid >> 6;
    int l   = tid & 63;
    int lr  = l & 15;
    int lg  = l >> 4;

    // stage pre-swizzled B table: coalesced 16B/lane
    #pragma unroll
    for (int it = 0; it < 4; ++it) {
        int s = tid + 256 * it;
        *(ushort8*)&ldsB[(size_t)s * 8] = *(const ushort8*)&Wf[(size_t)s * 8];
    }
    __syncthreads();

    int flat0 = (blockIdx.x * 4 + wid) * 64;

    int rowm[4];
    size_t hbase[4];
    #pragma unroll
    for (int m = 0; m < 4; ++m) {
        int row = flat0 + 16 * m + lr;
        rowm[m] = row;
        if (row < TOT) {
            int b = row >= Ec;
            int i = row - b * Ec;
            int srow = src_perm[i];
            hbase[m] = ((size_t)b * Nc + srow) * Dc;
        } else {
            hbase[m] = 0;
        }
    }

    float biasv[4];
    #pragma unroll
    for (int n = 0; n < 4; ++n) biasv[n] = bias[16 * n + lr];

    f32x4 acc[4][4];
    #pragma unroll
    for (int m = 0; m < 4; ++m)
        #pragma unroll
        for (int n = 0; n < 4; ++n) {
            f32x4 z = {biasv[n], biasv[n], biasv[n], biasv[n]};
            acc[m][n] = z;
        }

    #pragma unroll
    for (int kc = 0; kc < 4; ++kc) {
        short8 a[4];
        #pragma unroll
        for (int m = 0; m < 4; ++m) {
            const unsigned short* p;
            if (kc < 2) p = g + (size_t)rowm[m] * Dc + kc * 32 + lg * 8;
            else        p = h + hbase[m] + (kc - 2) * 32 + lg * 8;
            a[m] = *(const short8*)p;
        }
        short8 bfr[4];
        #pragma unroll
        for (int n = 0; n < 4; ++n)
            bfr[n] = *(const short8*)&ldsB[(size_t)((kc * 4 + n) * 64 + l) * 8];
        #pragma unroll
        for (int m = 0; m < 4; ++m)
            #pragma unroll
            for (int n = 0; n < 4; ++n)
                acc[m][n] = __builtin_amdgcn_mfma_f32_16x16x32_bf16(
                    a[m], bfr[n], acc[m][n], 0, 0, 0);
    }

    // relu -> bf16 -> per-m 16-row LDS transpose -> coalesced 16B/lane stores
    #pragma unroll
    for (int m = 0; m < 4; ++m) {
        #pragma unroll
        for (int n = 0; n < 4; ++n)
            #pragma unroll
            for (int r = 0; r < 4; ++r) {
                int row = lg * 4 + r;          // 0..15 within chunk
                int col = 16 * n + lr;
                slab[wid][row * 72 + col] = f2bf(fmaxf(acc[m][n][r], 0.0f));
            }
        // intra-wave DS ordering: reads see this m's writes; next m's writes
        // can't pass these reads (DS ops execute in program order per wave)
        #pragma unroll
        for (int i = 0; i < 2; ++i) {
            int row = i * 8 + (l >> 3);        // 0..15 within chunk
            int ch  = l & 7;
            ushort8 v = *(const ushort8*)&slab[wid][row * 72 + ch * 8];
            *(ushort8*)(g + (size_t)(flat0 + 16 * m + row) * Dc + ch * 8) = v;
        }
    }
}

// ---------------- aggregation: sequential segmented sum ----------------
__global__ __launch_bounds__(256) void agg_kernel(
    const unsigned short* __restrict__ g, float* __restrict__ agg,
    const int* __restrict__ offsets)
{
    int w    = (blockIdx.x * blockDim.x + threadIdx.x) >> 6;
    int lane = threadIdx.x & 63;
    if (w >= Bc * Nc) return;
    int b = w / Nc;
    int n = w - b * Nc;
    int beg = offsets[n], end = offsets[n + 1];
    size_t gb = (size_t)b * Ec;
    float s = 0.0f;
    for (int i = beg; i < end; ++i)
        s += bf2f(g[(gb + i) * Dc + lane]);
    agg[(size_t)w * Dc + lane] = s;
}

// ---------------- node MLP: h = relu(relu(h @ fv_W + fv_b) + agg) ---------
__global__ __launch_bounds__(256) void node_kernel(
    unsigned short* __restrict__ h, const float* __restrict__ agg,
    const float* __restrict__ W /* [64][64] */, const float* __restrict__ bias)
{
    int t = blockIdx.x * blockDim.x + threadIdx.x;
    if (t >= Bc * Nc) return;
    unsigned short* hr = h + (size_t)t * Dc;
    const float* ag = agg + (size_t)t * Dc;

    float acc[Dc];
    #pragma unroll
    for (int d = 0; d < Dc; ++d) acc[d] = bias[d];

    #pragma unroll 1
    for (int kc = 0; kc < Dc; kc += 8) {
        ushort8 hv = *(const ushort8*)(hr + kc);
        float in[8];
        #pragma unroll
        for (int j = 0; j < 8; ++j) in[j] = bf2f(hv[j]);
        #pragma unroll
        for (int kk = 0; kk < 8; ++kk) {
            const float* wr = W + (kc + kk) * Dc;   // wave-uniform -> s_load
            #pragma unroll
            for (int d = 0; d < Dc; ++d) acc[d] = fmaf(in[kk], wr[d], acc[d]);
        }
    }

    #pragma unroll
    for (int kc = 0; kc < Dc; kc += 8) {
        ushort8 v;
        #pragma unroll
        for (int j = 0; j < 8; ++j) {
            float a = ag[kc + j];
            v[j] = f2bf(fmaxf(fmaxf(acc[kc + j], 0.0f) + a, 0.0f));
        }
        *(ushort8*)(hr + kc) = v;
    }
}

// ---------------- epilogue ----------------
__global__ __launch_bounds__(256) void score_kernel(
    const unsigned short* __restrict__ h, const float* __restrict__ x,
    const float* __restrict__ fW, const float* __restrict__ fb,
    float* __restrict__ scores)
{
    int gt   = blockIdx.x * blockDim.x + threadIdx.x;
    int w    = gt >> 6;
    int lane = threadIdx.x & 63;
    if (w >= Bc * Nc) return;
    float v = bf2f(h[(size_t)w * Dc + lane]) * fW[lane];
    #pragma unroll
    for (int off = 32; off > 0; off >>= 1) v += __shfl_down(v, off);
    if (lane == 0) {
        float sc = v + fb[0];
        if (x[w * 3] > 0.5f) sc = -INFINITY;
        scores[w] = sc;
    }
}

__global__ __launch_bounds__(1024) void reduce_kernel(
    const float* __restrict__ scores, float* __restrict__ red)
{
    int b = blockIdx.x;
    const float* s = scores + (size_t)b * Nc;
    __shared__ float sm[16];
    int tid = threadIdx.x, lane = tid & 63, wid = tid >> 6;

    float m = -INFINITY;
    for (int i = tid; i < Nc; i += 1024) m = fmaxf(m, s[i]);
    #pragma unroll
    for (int off = 32; off > 0; off >>= 1) m = fmaxf(m, __shfl_down(m, off));
    if (lane == 0) sm[wid] = m;
    __syncthreads();
    if (tid == 0) {
        float mm = sm[0];
        for (int i = 1; i < 16; ++i) mm = fmaxf(mm, sm[i]);
        sm[0] = mm;
    }
    __syncthreads();
    float M = sm[0];
    __syncthreads();

    float sum = 0.0f;
    for (int i = tid; i < Nc; i += 1024) sum += expf(s[i] - M);
    #pragma unroll
    for (int off = 32; off > 0; off >>= 1) sum += __shfl_down(sum, off);
    if (lane == 0) sm[wid] = sum;
    __syncthreads();
    if (tid == 0) {
        float tot = 0.0f;
        for (int i = 0; i < 16; ++i) tot += sm[i];
        red[b * 2 + 0] = M;
        red[b * 2 + 1] = logf(tot);
    }
}

// clamp -inf to large finite negative (|(-inf)-(-inf)|=NaN fails harness).
__global__ __launch_bounds__(256) void final_kernel(
    const float* __restrict__ scores, const float* __restrict__ red,
    float* __restrict__ out)
{
    int i = blockIdx.x * blockDim.x + threadIdx.x;
    if (i >= Bc * Nc) return;
    int b = i / Nc;
    float v = scores[i] - red[b * 2] - red[b * 2 + 1];
    out[i] = fmaxf(v, -3.0e38f);
}

extern "C" void kernel_launch(void* const* d_in, const int* in_sizes, int n_in,
                              void* d_out, int out_size, void* d_ws, size_t ws_size,
                              hipStream_t stream)
{
    const float* x     = (const float*)d_in[0];
    const int*   ei    = (const int*)d_in[1];
    const float* ea    = (const float*)d_in[2];
    const float* pv_W  = (const float*)d_in[3];
    const float* pv_b  = (const float*)d_in[4];
    const float* pe_W  = (const float*)d_in[5];
    const float* pe_b  = (const float*)d_in[6];
    const float* fe_W  = (const float*)d_in[7];
    const float* fe_b  = (const float*)d_in[8];
    const float* fv_W  = (const float*)d_in[9];
    const float* fv_b  = (const float*)d_in[10];
    const float* fin_W = (const float*)d_in[11];
    const float* fin_b = (const float*)d_in[12];
    float* out = (float*)d_out;

    unsigned short* g_bf = (unsigned short*)d_ws;                 // TOT_PAD*64
    unsigned short* h_bf = g_bf + (size_t)TOT_PAD * Dc;           // B*N*64
    unsigned short* Wf   = h_bf + (size_t)Bc * Nc * Dc;           // 3*16K bf16
    float* agg    = (float*)(Wf + 3 * 1024 * 8);                  // B*N*64
    float* scores = agg + (size_t)Bc * Nc * Dc;                   // B*N
    float* red    = scores + (size_t)Bc * Nc;                     // 4
    int* counts   = (int*)(red + 4);                              // N
    int* offsets  = counts + Nc;                                  // N+1
    int* cursor   = offsets + Nc + 1;                             // N
    int* bsum     = cursor + Nc;                                  // SCAN_NBLK (256)
    int* elist    = bsum + 256;                                   // E
    int* src_perm = elist + Ec;                                   // E

    const int* src = ei;
    const int* dst = ei + Ec;

    csr_zero<<<(Nc + 255) / 256, 256, 0, stream>>>(counts);
    csr_count<<<(Ec + 255) / 256, 256, 0, stream>>>(dst, counts);
    scan_partial<<<SCAN_NBLK, 256, 0, stream>>>(counts, bsum);
    scan_bsum<<<1, 256, 0, stream>>>(bsum);
    scan_final<<<SCAN_NBLK, 256, 0, stream>>>(counts, bsum, offsets, cursor);
    csr_fill<<<(Ec + 255) / 256, 256, 0, stream>>>(dst, src, cursor, elist, src_perm);

    prep_W<<<(3 * 1024 + 255) / 256, 256, 0, stream>>>(fe_W, Wf);
    init_h_kernel<<<(Bc * Nc * Dc + 255) / 256, 256, 0, stream>>>(x, pv_W, pv_b, h_bf);
    init_g_kernel<<<((size_t)Ec * 64 + 255) / 256, 256, 0, stream>>>(ea, pe_W, pe_b, elist, g_bf);

    for (int l = 0; l < 3; ++l) {
        edge_kernel<<<NT_TILES / 4, 256, 0, stream>>>(
            g_bf, h_bf, src_perm, Wf + (size_t)l * 1024 * 8, fe_b + l * Dc);
        agg_kernel<<<((size_t)Bc * Nc * 64 + 255) / 256, 256, 0, stream>>>(
            g_bf, agg, offsets);
        node_kernel<<<(Bc * Nc + 255) / 256, 256, 0, stream>>>(
            h_bf, agg, fv_W + (size_t)l * Dc * Dc, fv_b + l * Dc);
    }

    score_kernel<<<((size_t)Bc * Nc * 64 + 255) / 256, 256, 0, stream>>>(
        h_bf, x, fin_W, fin_b, scores);
    reduce_kernel<<<Bc, 1024, 0, stream>>>(scores, red);
    final_kernel<<<(Bc * Nc + 255) / 256, 256, 0, stream>>>(scores, red, out);
}

// Round 11
// 521.389 us; speedup vs baseline: 1.0277x; 1.0277x over previous
//
#include <hip/hip_runtime.h>
#include <math.h>

constexpr int Bc = 2;
constexpr int Nc = 50000;
constexpr int Ec = 250000;
constexpr int Dc = 64;
constexpr int TOT = Bc * Ec;            // 500000
constexpr int NT_TILES = 7816;          // ceil(TOT/64)
constexpr int TOT_PAD = NT_TILES * 64;  // 500224
constexpr int SCAN_NBLK = (Nc + 255) / 256;   // 196

typedef __attribute__((ext_vector_type(8))) short short8;
typedef __attribute__((ext_vector_type(8))) unsigned short ushort8;
typedef __attribute__((ext_vector_type(4))) float f32x4;

__device__ inline unsigned short f2bf(float f) {
    unsigned int u = __builtin_bit_cast(unsigned int, f);
    unsigned int r = (u + 0x7fffu + ((u >> 16) & 1u)) >> 16;
    return (unsigned short)r;
}
__device__ inline float bf2f(unsigned short s) {
    unsigned int u = ((unsigned int)s) << 16;
    return __builtin_bit_cast(float, u);
}

// ---------------- CSR build (by dst) ----------------
__global__ __launch_bounds__(256) void csr_zero(int* __restrict__ counts)
{
    int i = blockIdx.x * 256 + threadIdx.x;
    if (i < Nc) counts[i] = 0;
}

__global__ __launch_bounds__(256) void csr_count(const int* __restrict__ dst,
                                                 int* __restrict__ counts)
{
    int e = blockIdx.x * 256 + threadIdx.x;
    if (e < Ec) atomicAdd(&counts[dst[e]], 1);
}

// hierarchical scan, level 1: block-local inclusive scan, emit block sums
__global__ __launch_bounds__(256) void scan_partial(const int* __restrict__ counts,
                                                    int* __restrict__ bsum)
{
    __shared__ int sm[256];
    int tid = threadIdx.x;
    int i = blockIdx.x * 256 + tid;
    int c = (i < Nc) ? counts[i] : 0;
    sm[tid] = c;
    __syncthreads();
    #pragma unroll
    for (int off = 1; off < 256; off <<= 1) {
        int v = (tid >= off) ? sm[tid - off] : 0;
        __syncthreads();
        sm[tid] += v;
        __syncthreads();
    }
    if (tid == 255) bsum[blockIdx.x] = sm[255];
}

// level 2: exclusive scan of block sums (1 block)
__global__ __launch_bounds__(256) void scan_bsum(int* __restrict__ bsum)
{
    __shared__ int sm[256];
    int tid = threadIdx.x;
    int v = (tid < SCAN_NBLK) ? bsum[tid] : 0;
    sm[tid] = v;
    __syncthreads();
    #pragma unroll
    for (int off = 1; off < 256; off <<= 1) {
        int u = (tid >= off) ? sm[tid - off] : 0;
        __syncthreads();
        sm[tid] += u;
        __syncthreads();
    }
    if (tid < SCAN_NBLK) bsum[tid] = sm[tid] - v;   // exclusive
}

// level 3: offsets/cursor = bbase + local exclusive scan
__global__ __launch_bounds__(256) void scan_final(const int* __restrict__ counts,
                                                  const int* __restrict__ bsum,
                                                  int* __restrict__ offsets,
                                                  int* __restrict__ cursor)
{
    __shared__ int sm[256];
    int tid = threadIdx.x;
    int i = blockIdx.x * 256 + tid;
    int c = (i < Nc) ? counts[i] : 0;
    sm[tid] = c;
    __syncthreads();
    #pragma unroll
    for (int off = 1; off < 256; off <<= 1) {
        int v = (tid >= off) ? sm[tid - off] : 0;
        __syncthreads();
        sm[tid] += v;
        __syncthreads();
    }
    if (i < Nc) {
        int o = bsum[blockIdx.x] + sm[tid] - c;
        offsets[i] = o;
        cursor[i] = o;
    }
    if (i == 0) offsets[Nc] = Ec;
}

// records elist (slot -> edge) and src_perm (slot -> src node)
__global__ __launch_bounds__(256) void csr_fill(const int* __restrict__ dst,
                                                const int* __restrict__ src,
                                                int* __restrict__ cursor,
                                                int* __restrict__ elist,
                                                int* __restrict__ src_perm)
{
    int e = blockIdx.x * 256 + threadIdx.x;
    if (e < Ec) {
        int p = atomicAdd(&cursor[dst[e]], 1);
        elist[p] = e;
        src_perm[p] = src[e];
    }
}

// ---------------- weight pre-swizzle: fe_W -> bf16 MFMA B-fragment table ----
// Layout per layer: 16 frags (kc*4+n) x 64 lanes x 8 bf16 = 16KB.
// B frag: col = lane&15, k = 32*kc + (lane>>4)*8 + j.
__global__ __launch_bounds__(256) void prep_W(const float* __restrict__ fe_W,
                                              unsigned short* __restrict__ Wf)
{
    int t = blockIdx.x * 256 + threadIdx.x;     // 3*1024 slots
    if (t >= 3 * 1024) return;
    int l  = t >> 10;
    int s  = t & 1023;
    int frag = s >> 6;
    int sl   = s & 63;
    int kc = frag >> 2;
    int n  = frag & 3;
    int kbase = 32 * kc + (sl >> 4) * 8;
    int col   = 16 * n + (sl & 15);
    const float* W = fe_W + (size_t)l * 2 * Dc * Dc;
    ushort8 v;
    #pragma unroll
    for (int j = 0; j < 8; ++j) v[j] = f2bf(W[(size_t)(kbase + j) * Dc + col]);
    *(ushort8*)&Wf[(size_t)t * 8] = v;
}

// ---------------- init ----------------
__global__ __launch_bounds__(256) void init_h_kernel(
    const float* __restrict__ x, const float* __restrict__ pv_W,
    const float* __restrict__ pv_b, unsigned short* __restrict__ h)
{
    int idx = blockIdx.x * blockDim.x + threadIdx.x;
    if (idx >= Bc * Nc * Dc) return;
    int bn = idx >> 6;
    int d  = idx & 63;
    float x0 = x[bn * 3 + 0];
    float x1 = x[bn * 3 + 1];
    int s = (x0 > 0.5f) ? 0 : ((x1 > 0.5f) ? 1 : 2);
    float v = pv_W[s * Dc + d] + pv_b[d];
    h[idx] = f2bf(fmaxf(v, 0.0f));
}

// g0 in slot order, SINGLE shared copy (batches identical at layer 0).
// 4 rows per wave: 4 independent chains, float4 ea loads, pe_W col in regs.
__global__ __launch_bounds__(256) void init_g_kernel(
    const float* __restrict__ ea, const float* __restrict__ pe_W,
    const float* __restrict__ pe_b, const int* __restrict__ elist,
    unsigned short* __restrict__ g0)
{
    int wave = (blockIdx.x * 256 + threadIdx.x) >> 6;
    int lane = threadIdx.x & 63;
    int p0 = wave * 4;
    if (p0 >= Ec) return;                       // Ec % 4 == 0

    float wcol[16];
    #pragma unroll
    for (int t = 0; t < 16; ++t) wcol[t] = pe_W[t * Dc + lane];
    float bv = pe_b[lane];

    int e[4];
    #pragma unroll
    for (int r = 0; r < 4; ++r) e[r] = elist[p0 + r];

    #pragma unroll
    for (int r = 0; r < 4; ++r) {
        const float4* row = (const float4*)(ea + (size_t)e[r] * 16);
        float4 a0 = row[0], a1 = row[1], a2 = row[2], a3 = row[3];
        float av[16] = {a0.x, a0.y, a0.z, a0.w, a1.x, a1.y, a1.z, a1.w,
                        a2.x, a2.y, a2.z, a2.w, a3.x, a3.y, a3.z, a3.w};
        float acc = bv;
        #pragma unroll
        for (int t = 0; t < 16; ++t) acc = fmaf(av[t], wcol[t], acc);
        g0[(size_t)(p0 + r) * Dc + lane] = f2bf(fmaxf(acc, 0.0f));
    }
}

// ---------------- edge MLP via MFMA ----------------
// 4 waves/block; each wave owns 64 consecutive permuted edge-rows.
// A = [gin_row ; h_src_row] (bf16), B = Wf (pre-swizzled bf16 frags),
// D = relu(A@B + bias) written to g (own rows only; in place for l>=1).
// mirror=1 (layer 0): gin indexed by slot = row - b*Ec (shared g0).
// NOTE: g and gin may alias (l>=1) -> no __restrict__ on them.
// Fragment layouts (gfx950 16x16x32 bf16, HW-verified round 5 self-check):
//   A: row = lane&15, k = (lane>>4)*8 + j
//   B: col = lane&15, k = (lane>>4)*8 + j
//   D: col = lane&15, row = (lane>>4)*4 + reg
__global__ __launch_bounds__(256) void edge_kernel(
    unsigned short* g, const unsigned short* gin, int mirror,
    const unsigned short* __restrict__ h,
    const int* __restrict__ src_perm,
    const unsigned short* __restrict__ Wf /* [16][64][8] bf16 */,
    const float* __restrict__ bias)
{
    __shared__ unsigned short ldsB[16 * 64 * 8];   // 16KB
    __shared__ unsigned short slab[4][16 * 72];    // 9KB: per-wave 16-row chunk

    int tid = threadIdx.x;
    int wid = tid >> 6;
    int l   = tid & 63;
    int lr  = l & 15;
    int lg  = l >> 4;

    // stage pre-swizzled B table: coalesced 16B/lane
    #pragma unroll
    for (int it = 0; it < 4; ++it) {
        int s = tid + 256 * it;
        *(ushort8*)&ldsB[(size_t)s * 8] = *(const ushort8*)&Wf[(size_t)s * 8];
    }
    __syncthreads();

    int flat0 = (blockIdx.x * 4 + wid) * 64;

    int rowin[4];
    size_t hbase[4];
    #pragma unroll
    for (int m = 0; m < 4; ++m) {
        int row = flat0 + 16 * m + lr;
        int rr = (row < TOT) ? row : 0;
        int b = rr >= Ec;
        int i = rr - b * Ec;
        rowin[m] = mirror ? i : rr;
        hbase[m] = ((size_t)b * Nc + src_perm[i]) * Dc;
    }

    float biasv[4];
    #pragma unroll
    for (int n = 0; n < 4; ++n) biasv[n] = bias[16 * n + lr];

    f32x4 acc[4][4];
    #pragma unroll
    for (int m = 0; m < 4; ++m)
        #pragma unroll
        for (int n = 0; n < 4; ++n) {
            f32x4 z = {biasv[n], biasv[n], biasv[n], biasv[n]};
            acc[m][n] = z;
        }

    #pragma unroll
    for (int kc = 0; kc < 4; ++kc) {
        short8 a[4];
        #pragma unroll
        for (int m = 0; m < 4; ++m) {
            const unsigned short* p;
            if (kc < 2) p = gin + (size_t)rowin[m] * Dc + kc * 32 + lg * 8;
            else        p = h + hbase[m] + (kc - 2) * 32 + lg * 8;
            a[m] = *(const short8*)p;
        }
        short8 bfr[4];
        #pragma unroll
        for (int n = 0; n < 4; ++n)
            bfr[n] = *(const short8*)&ldsB[(size_t)((kc * 4 + n) * 64 + l) * 8];
        #pragma unroll
        for (int m = 0; m < 4; ++m)
            #pragma unroll
            for (int n = 0; n < 4; ++n)
                acc[m][n] = __builtin_amdgcn_mfma_f32_16x16x32_bf16(
                    a[m], bfr[n], acc[m][n], 0, 0, 0);
    }

    // relu -> bf16 -> per-m 16-row LDS transpose -> coalesced 16B/lane stores
    #pragma unroll
    for (int m = 0; m < 4; ++m) {
        #pragma unroll
        for (int n = 0; n < 4; ++n)
            #pragma unroll
            for (int r = 0; r < 4; ++r) {
                int row = lg * 4 + r;          // 0..15 within chunk
                int col = 16 * n + lr;
                slab[wid][row * 72 + col] = f2bf(fmaxf(acc[m][n][r], 0.0f));
            }
        // intra-wave DS ordering: reads see this m's writes; next m's writes
        // can't pass these reads (DS ops execute in program order per wave)
        #pragma unroll
        for (int i = 0; i < 2; ++i) {
            int row = i * 8 + (l >> 3);        // 0..15 within chunk
            int ch  = l & 7;
            ushort8 v = *(const ushort8*)&slab[wid][row * 72 + ch * 8];
            *(ushort8*)(g + (size_t)(flat0 + 16 * m + row) * Dc + ch * 8) = v;
        }
    }
}

// ---------------- fused aggregation + node MLP ----------------
// One wave per (b,n) row. agg = segmented sum of dst-sorted g rows (lane=ch);
// node MLP via __shfl broadcast: acc[lane] = sum_k h[k] * W[k][lane].
// h updated in place: h = relu(relu(h@W+b) + agg). No agg buffer.
__global__ __launch_bounds__(256) void aggnode_kernel(
    const unsigned short* __restrict__ g, unsigned short* __restrict__ h,
    const int* __restrict__ offsets,
    const float* __restrict__ W /* [64][64] */, const float* __restrict__ bias)
{
    int w    = (blockIdx.x * 256 + threadIdx.x) >> 6;
    int lane = threadIdx.x & 63;
    if (w >= Bc * Nc) return;
    int b = w / Nc;
    int n = w - b * Nc;
    int beg = offsets[n], end = offsets[n + 1];
    size_t gb = (size_t)b * Ec;
    float s = 0.0f;
    for (int i = beg; i < end; ++i)
        s += bf2f(g[(gb + i) * Dc + lane]);

    float hv = bf2f(h[(size_t)w * Dc + lane]);
    float acc = bias[lane];
    #pragma unroll
    for (int k = 0; k < 64; ++k) {
        float hk = __shfl(hv, k);               // readlane -> SGPR operand
        acc = fmaf(hk, W[k * Dc + lane], acc);  // W row: coalesced, L1-hit
    }
    float o = fmaxf(fmaxf(acc, 0.0f) + s, 0.0f);
    h[(size_t)w * Dc + lane] = f2bf(o);
}

// ---------------- epilogue ----------------
__global__ __launch_bounds__(256) void score_kernel(
    const unsigned short* __restrict__ h, const float* __restrict__ x,
    const float* __restrict__ fW, const float* __restrict__ fb,
    float* __restrict__ scores)
{
    int gt   = blockIdx.x * blockDim.x + threadIdx.x;
    int w    = gt >> 6;
    int lane = threadIdx.x & 63;
    if (w >= Bc * Nc) return;
    float v = bf2f(h[(size_t)w * Dc + lane]) * fW[lane];
    #pragma unroll
    for (int off = 32; off > 0; off >>= 1) v += __shfl_down(v, off);
    if (lane == 0) {
        float sc = v + fb[0];
        if (x[w * 3] > 0.5f) sc = -INFINITY;
        scores[w] = sc;
    }
}

__global__ __launch_bounds__(1024) void reduce_kernel(
    const float* __restrict__ scores, float* __restrict__ red)
{
    int b = blockIdx.x;
    const float* s = scores + (size_t)b * Nc;
    __shared__ float sm[16];
    int tid = threadIdx.x, lane = tid & 63, wid = tid >> 6;

    float m = -INFINITY;
    for (int i = tid; i < Nc; i += 1024) m = fmaxf(m, s[i]);
    #pragma unroll
    for (int off = 32; off > 0; off >>= 1) m = fmaxf(m, __shfl_down(m, off));
    if (lane == 0) sm[wid] = m;
    __syncthreads();
    if (tid == 0) {
        float mm = sm[0];
        for (int i = 1; i < 16; ++i) mm = fmaxf(mm, sm[i]);
        sm[0] = mm;
    }
    __syncthreads();
    float M = sm[0];
    __syncthreads();

    float sum = 0.0f;
    for (int i = tid; i < Nc; i += 1024) sum += expf(s[i] - M);
    #pragma unroll
    for (int off = 32; off > 0; off >>= 1) sum += __shfl_down(sum, off);
    if (lane == 0) sm[wid] = sum;
    __syncthreads();
    if (tid == 0) {
        float tot = 0.0f;
        for (int i = 0; i < 16; ++i) tot += sm[i];
        red[b * 2 + 0] = M;
        red[b * 2 + 1] = logf(tot);
    }
}

// clamp -inf to large finite negative (|(-inf)-(-inf)|=NaN fails harness).
__global__ __launch_bounds__(256) void final_kernel(
    const float* __restrict__ scores, const float* __restrict__ red,
    float* __restrict__ out)
{
    int i = blockIdx.x * blockDim.x + threadIdx.x;
    if (i >= Bc * Nc) return;
    int b = i / Nc;
    float v = scores[i] - red[b * 2] - red[b * 2 + 1];
    out[i] = fmaxf(v, -3.0e38f);
}

extern "C" void kernel_launch(void* const* d_in, const int* in_sizes, int n_in,
                              void* d_out, int out_size, void* d_ws, size_t ws_size,
                              hipStream_t stream)
{
    const float* x     = (const float*)d_in[0];
    const int*   ei    = (const int*)d_in[1];
    const float* ea    = (const float*)d_in[2];
    const float* pv_W  = (const float*)d_in[3];
    const float* pv_b  = (const float*)d_in[4];
    const float* pe_W  = (const float*)d_in[5];
    const float* pe_b  = (const float*)d_in[6];
    const float* fe_W  = (const float*)d_in[7];
    const float* fe_b  = (const float*)d_in[8];
    const float* fv_W  = (const float*)d_in[9];
    const float* fv_b  = (const float*)d_in[10];
    const float* fin_W = (const float*)d_in[11];
    const float* fin_b = (const float*)d_in[12];
    float* out = (float*)d_out;

    unsigned short* g_bf = (unsigned short*)d_ws;                 // TOT_PAD*64
    unsigned short* g0   = g_bf + (size_t)TOT_PAD * Dc;           // Ec*64 (shared)
    unsigned short* h_bf = g0 + (size_t)Ec * Dc;                  // B*N*64
    unsigned short* Wf   = h_bf + (size_t)Bc * Nc * Dc;           // 3*16K bf16
    float* scores = (float*)(Wf + 3 * 1024 * 8);                  // B*N
    float* red    = scores + (size_t)Bc * Nc;                     // 4
    int* counts   = (int*)(red + 4);                              // N
    int* offsets  = counts + Nc;                                  // N+1
    int* cursor   = offsets + Nc + 1;                             // N
    int* bsum     = cursor + Nc;                                  // SCAN_NBLK (256)
    int* elist    = bsum + 256;                                   // E
    int* src_perm = elist + Ec;                                   // E

    const int* src = ei;
    const int* dst = ei + Ec;

    csr_zero<<<(Nc + 255) / 256, 256, 0, stream>>>(counts);
    csr_count<<<(Ec + 255) / 256, 256, 0, stream>>>(dst, counts);
    scan_partial<<<SCAN_NBLK, 256, 0, stream>>>(counts, bsum);
    scan_bsum<<<1, 256, 0, stream>>>(bsum);
    scan_final<<<SCAN_NBLK, 256, 0, stream>>>(counts, bsum, offsets, cursor);
    csr_fill<<<(Ec + 255) / 256, 256, 0, stream>>>(dst, src, cursor, elist, src_perm);

    prep_W<<<(3 * 1024 + 255) / 256, 256, 0, stream>>>(fe_W, Wf);
    init_h_kernel<<<(Bc * Nc * Dc + 255) / 256, 256, 0, stream>>>(x, pv_W, pv_b, h_bf);
    init_g_kernel<<<((Ec / 4) * 64 + 255) / 256, 256, 0, stream>>>(
        ea, pe_W, pe_b, elist, g0);

    for (int l = 0; l < 3; ++l) {
        edge_kernel<<<NT_TILES / 4, 256, 0, stream>>>(
            g_bf, (l == 0) ? g0 : g_bf, (l == 0) ? 1 : 0,
            h_bf, src_perm, Wf + (size_t)l * 1024 * 8, fe_b + l * Dc);
        aggnode_kernel<<<((size_t)Bc * Nc * 64 + 255) / 256, 256, 0, stream>>>(
            g_bf, h_bf, offsets, fv_W + (size_t)l * Dc * Dc, fv_b + l * Dc);
    }

    score_kernel<<<((size_t)Bc * Nc * 64 + 255) / 256, 256, 0, stream>>>(
        h_bf, x, fin_W, fin_b, scores);
    reduce_kernel<<<Bc, 1024, 0, stream>>>(scores, red);
    final_kernel<<<(Bc * Nc + 255) / 256, 256, 0, stream>>>(scores, red, out);
}